// Round 6
// baseline (262.629 us; speedup 1.0000x reference)
//
#include <hip/hip_runtime.h>
#include <math.h>

// Problem constants (match reference)
#define B_  4
#define NQ_ 8192
#define D_  256
#define H_  8
#define L_  4
#define K_  4
#define DH_ 32
#define NV_ 5440

// Padded value-slab geometry (per (b,h)): levels with 1-px zero border
// L0: 66x66=4356, L1: 34x34=1156, L2: 18x18=324, L3: 10x10=100 -> 5936 rows
#define SLAB_ 5936

typedef short bf16x8 __attribute__((ext_vector_type(8)));
typedef float f32x4  __attribute__((ext_vector_type(4)));
typedef float f32x8  __attribute__((ext_vector_type(8)));
typedef unsigned short u16x8 __attribute__((ext_vector_type(8)));

typedef __attribute__((address_space(3))) ushort lds_ushort;
typedef const __attribute__((address_space(1))) ushort glb_ushort;

__device__ __forceinline__ ushort f2bf(float f) {
    union { float f; unsigned u; } v; v.f = f;
    return (ushort)((v.u + 0x7FFF + ((v.u >> 16) & 1)) >> 16);
}
__device__ __forceinline__ float bf2f(ushort u) {
    union { unsigned u; float f; } v; v.u = ((unsigned)u) << 16;
    return v.f;
}
// async global->LDS, 16B per lane; lds dest must be uniform-base + lane*16
__device__ __forceinline__ void gload_lds16(const ushort* g, ushort* l) {
    __builtin_amdgcn_global_load_lds((glb_ushort*)(unsigned long long)g,
                                     (lds_ushort*)(unsigned)(unsigned long long)l,
                                     16, 0, 0);
}

// ---------------------------------------------------------------------------
// k_prep: all conversions + slab zeroing in ONE kernel (block-range dispatch)
//  [0,4096):      query f32 -> qbf bf16          (8 elem/thread)
//  [4096,6816):   value f32 -> valbf bf16
//  [6816,9784):   zero vperm slabs (16B/thread)
//  [9784,10040):  Wv transpose-convert -> Wvt
//  [10040,10296): Wo transpose-convert -> Wot
//  [10296,10584): {Wt|Wf|Wlv|Wp} transpose-convert -> Wqt
// ---------------------------------------------------------------------------
__global__ __launch_bounds__(256) void k_prep(const float* __restrict__ query,
                                              const float* __restrict__ value,
                                              const float* __restrict__ Wv,
                                              const float* __restrict__ Wo,
                                              const float* __restrict__ Wt,
                                              const float* __restrict__ Wf,
                                              const float* __restrict__ Wlv,
                                              const float* __restrict__ Wp,
                                              ushort* __restrict__ qbf,
                                              ushort* __restrict__ valbf,
                                              uint4* __restrict__ vzero,
                                              ushort* __restrict__ Wvt,
                                              ushort* __restrict__ Wot,
                                              ushort* __restrict__ Wqt) {
    const int bk = blockIdx.x;
    const int t  = threadIdx.x;
    if (bk < 6816) {
        const float* in; ushort* out; int blk;
        if (bk < 4096) { in = query; out = qbf; blk = bk; }
        else           { in = value; out = valbf; blk = bk - 4096; }
        const size_t base = ((size_t)blk * 256 + t) * 8;
        const float4 a = *(const float4*)(in + base);
        const float4 b = *(const float4*)(in + base + 4);
        u16x8 u;
        u[0] = f2bf(a.x); u[1] = f2bf(a.y); u[2] = f2bf(a.z); u[3] = f2bf(a.w);
        u[4] = f2bf(b.x); u[5] = f2bf(b.y); u[6] = f2bf(b.z); u[7] = f2bf(b.w);
        *(u16x8*)(out + base) = u;
    } else if (bk < 9784) {
        vzero[(size_t)(bk - 6816) * 256 + t] = make_uint4(0, 0, 0, 0);
    } else if (bk < 10296) {
        const float* in; ushort* out; int n;
        if (bk < 10040) { in = Wv; out = Wvt; n = bk - 9784; }
        else            { in = Wo; out = Wot; n = bk - 10040; }
        out[n * 256 + t] = f2bf(in[t * 256 + n]);
    } else {
        const int n = bk - 10296;
        float v;
        if (n < 64)       v = Wt[t * 64 + n];
        else if (n < 128) v = Wf[t * 64 + (n - 64)];
        else if (n < 160) v = Wlv[t * 32 + (n - 128)];
        else              v = Wp[t * 128 + (n - 160)];
        Wqt[n * 256 + t] = f2bf(v);
    }
}

// ---------------------------------------------------------------------------
// MFMA GEMM: C[M][N] = A[M][256](bf16) @ Bt[N][256](bf16)^T (+bias)
// tile 128 x NT, 4 waves 2x2, 16x16x32 bf16, BK=32, async 16B staging,
// LDS-transposed coalesced epilogue.
// MODE 0: out proj  -> f32 C[row*256+col] = acc + bias[col]
// MODE 1: vproj     -> bf16 padded slab write (zero-border layout)
// MODE 2: qproj     -> f32 logits[row*288+col] = acc (bias in k_epi)
// ---------------------------------------------------------------------------
template<int NT, int MODE>
__global__ __launch_bounds__(256) void k_gemm(const ushort* __restrict__ A,
                                              const ushort* __restrict__ Bt,
                                              const float* __restrict__ bias,
                                              void* __restrict__ Cp) {
    constexpr int NFN  = NT / 32;             // n-frags per wave (128->4, 96->3)
    constexpr int SW   = NT + 4;              // epilogue LDS stride (floats)
    constexpr int SSTG = (128 * 32 + NT * 32) * 2;
    constexpr int SEPI = 32 * SW * 4;
    constexpr int SMEM = (SSTG > SEPI) ? SSTG : SEPI;
    __shared__ __align__(16) char smem[SMEM];
    ushort* As  = (ushort*)smem;
    ushort* Bs  = As + 128 * 32;
    float*  sep = (float*)smem;

    const int m0   = blockIdx.x * 128;
    const int n0   = blockIdx.y * NT;
    const int t    = threadIdx.x;
    const int w    = t >> 6;
    const int lane = t & 63;
    const int wm   = (w >> 1) * 64;
    const int wn   = (w & 1) * (NT / 2);
    const int lm   = lane & 15;
    const int quad = lane >> 4;

    f32x4 acc[4][NFN];
    #pragma unroll
    for (int i = 0; i < 4; ++i)
        #pragma unroll
        for (int j = 0; j < NFN; ++j)
            acc[i][j] = (f32x4)(0.f);

    for (int kc = 0; kc < 256; kc += 32) {
        __syncthreads();                       // prev ds_reads done before overwrite
        #pragma unroll
        for (int i = 0; i < 4; ++i) {          // A: 1024 x 16B chunks
            const int c = t + i * 256;
            gload_lds16(&A[(size_t)(m0 + (c >> 2)) * 256 + kc + (c & 3) * 8],
                        &As[c * 8]);
        }
        #pragma unroll
        for (int i = 0; i < 2; ++i) {          // B: NT*4 x 16B chunks
            const int c = t + i * 256;
            if (NT == 128 || c < NT * 4)       // whole waves active or skipped
                gload_lds16(&Bt[(size_t)(n0 + (c >> 2)) * 256 + kc + (c & 3) * 8],
                            &Bs[c * 8]);
        }
        __syncthreads();                       // drains vmcnt -> LDS valid

        bf16x8 af[4], bfr[NFN];
        #pragma unroll
        for (int mf = 0; mf < 4; ++mf)
            af[mf] = *(const bf16x8*)&As[(wm + mf * 16 + lm) * 32 + quad * 8];
        #pragma unroll
        for (int nf = 0; nf < NFN; ++nf)
            bfr[nf] = *(const bf16x8*)&Bs[(wn + nf * 16 + lm) * 32 + quad * 8];
        #pragma unroll
        for (int mf = 0; mf < 4; ++mf)
            #pragma unroll
            for (int nf = 0; nf < NFN; ++nf)
                acc[mf][nf] = __builtin_amdgcn_mfma_f32_16x16x32_bf16(
                    af[mf], bfr[nf], acc[mf][nf], 0, 0, 0);
    }

    // ---- epilogue: per-mf 32-row chunk through LDS, coalesced vector stores
    const int lr0 = (w >> 1) * 16;             // waves 0,1 -> rows 0-15; 2,3 -> 16-31
    #pragma unroll
    for (int mf = 0; mf < 4; ++mf) {
        __syncthreads();
        #pragma unroll
        for (int nf = 0; nf < NFN; ++nf)
            #pragma unroll
            for (int r = 0; r < 4; ++r)
                sep[(lr0 + quad * 4 + r) * SW + wn + nf * 16 + lm] = acc[mf][nf][r];
        __syncthreads();

        const int lr   = t >> 3;               // 32 rows, 8 threads each
        const int band = lr >> 4, ri = lr & 15;
        const int gr   = m0 + band * 64 + mf * 16 + ri;
        const int c0   = (t & 7) * (NT / 8);   // NT/8 cols per thread

        if (MODE == 0) {
            float* C = (float*)Cp;
            #pragma unroll
            for (int j = 0; j < NT / 32; ++j) {
                f32x4 v = *(f32x4*)&sep[lr * SW + c0 + j * 4];
                const int col = n0 + c0 + j * 4;
                v.x += bias[col]; v.y += bias[col + 1];
                v.z += bias[col + 2]; v.w += bias[col + 3];
                *(f32x4*)&C[(size_t)gr * 256 + col] = v;
            }
        } else if (MODE == 2) {
            float* C = (float*)Cp;
            #pragma unroll
            for (int j = 0; j < NT / 32; ++j)
                *(f32x4*)&C[(size_t)gr * 288 + n0 + c0 + j * 4] =
                    *(f32x4*)&sep[lr * SW + c0 + j * 4];
        } else {
            // padded bf16 slab write; index math once per thread per chunk
            const int b = gr / NV_, s = gr - b * NV_;
            const int l = (s >= 5376) ? 3 : (s >= 5120) ? 2 : (s >= 4096) ? 1 : 0;
            const int lsi_[4] = {0, 4096, 5120, 5376};
            const int po_[4]  = {0, 4356, 5512, 5836};
            const int o  = s - lsi_[l];
            const int Wl = 64 >> l;
            const int y  = o >> (6 - l);
            const int x  = o & (Wl - 1);
            const int prow = po_[l] + (y + 1) * (Wl + 2) + (x + 1);
            const int h   = (n0 + c0) >> 5;    // uniform across 16-col segment
            const int dh0 = (n0 + c0) & 31;
            ushort* dst = (ushort*)Cp + (((size_t)(b * H_ + h)) * SLAB_ + prow) * 32 + dh0;
            #pragma unroll
            for (int j2 = 0; j2 < 2; ++j2) {
                u16x8 u;
                #pragma unroll
                for (int e = 0; e < 8; ++e) {
                    const int cc = c0 + j2 * 8 + e;
                    u[e] = f2bf(sep[lr * SW + cc] + bias[n0 + cc]);
                }
                *(u16x8*)(dst + j2 * 8) = u;
            }
        }
    }
}

// ---------------------------------------------------------------------------
// Epilogue: logits[32768][288] (+bias) -> tanh/softmax/coords -> params
// params per (b,q): [H][L][8] = {attn0..3, xA, xB, yA, yB}
// ---------------------------------------------------------------------------
__global__ __launch_bounds__(256) void k_epi(const float* __restrict__ logits,
                                             const float* __restrict__ refpts,
                                             const float* __restrict__ bt,
                                             const float* __restrict__ bfq,
                                             const float* __restrict__ blv,
                                             const float* __restrict__ bp,
                                             float* __restrict__ params) {
    const int item = blockIdx.x * 256 + threadIdx.x;   // 32768*32 items
    const int qg = item >> 5;
    const int hl = item & 31;
    const int h = hl >> 2, l = hl & 3;
    const float* lgr = logits + (size_t)qg * 288;

    const float tA = tanhf(lgr[hl * 2 + 0] + bt[hl * 2 + 0]);
    const float tB = tanhf(lgr[hl * 2 + 1] + bt[hl * 2 + 1]);
    const float fA = tanhf(lgr[64 + hl * 2 + 0] + bfq[hl * 2 + 0]);
    const float fB = tanhf(lgr[64 + hl * 2 + 1] + bfq[hl * 2 + 1]);

    const float l0 = lgr[128 + h * 4 + 0] + blv[h * 4 + 0];
    const float l1 = lgr[128 + h * 4 + 1] + blv[h * 4 + 1];
    const float l2 = lgr[128 + h * 4 + 2] + blv[h * 4 + 2];
    const float l3 = lgr[128 + h * 4 + 3] + blv[h * 4 + 3];
    const float lm = fmaxf(fmaxf(l0, l1), fmaxf(l2, l3));
    const float e0 = __expf(l0 - lm), e1 = __expf(l1 - lm);
    const float e2 = __expf(l2 - lm), e3 = __expf(l3 - lm);
    const float lsum = e0 + e1 + e2 + e3;
    const float lwv = ((l == 0) ? e0 : (l == 1) ? e1 : (l == 2) ? e2 : e3) / lsum;

    const float p0 = lgr[160 + hl * 4 + 0] + bp[hl * 4 + 0];
    const float p1 = lgr[160 + hl * 4 + 1] + bp[hl * 4 + 1];
    const float p2 = lgr[160 + hl * 4 + 2] + bp[hl * 4 + 2];
    const float p3 = lgr[160 + hl * 4 + 3] + bp[hl * 4 + 3];
    const float pmx = fmaxf(fmaxf(p0, p1), fmaxf(p2, p3));
    const float q0e = __expf(p0 - pmx), q1e = __expf(p1 - pmx);
    const float q2e = __expf(p2 - pmx), q3e = __expf(p3 - pmx);
    const float inv = lwv / (q0e + q1e + q2e + q3e);

    const float rx = refpts[((size_t)qg * L_ + l) * 2 + 0];
    const float ry = refpts[((size_t)qg * L_ + l) * 2 + 1];
    const float Wlf = (float)(64 >> l);
    const float Hlf = (float)(64 >> l);
    const float xA = fminf(fmaxf(rx + tA / Wlf, 0.f), 1.f) * Wlf - 0.5f;
    const float xB = fminf(fmaxf(rx + tB / Wlf, 0.f), 1.f) * Wlf - 0.5f;
    const float yA = fminf(fmaxf(ry + fA / Hlf, 0.f), 1.f) * Hlf - 0.5f;
    const float yB = fminf(fmaxf(ry + fB / Hlf, 0.f), 1.f) * Hlf - 0.5f;

    float* pp = params + (size_t)qg * 256 + hl * 8;
    pp[0] = q0e * inv; pp[1] = q1e * inv; pp[2] = q2e * inv; pp[3] = q3e * inv;
    pp[4] = xA; pp[5] = xB; pp[6] = yA; pp[7] = yB;
}

// ---------------------------------------------------------------------------
// Bilinear sampling + attention accumulation -> mid bf16 [B*NQ][256]
// Thread = (ql, h, dh8); 16B gather loads; 8 queries per block.
// ---------------------------------------------------------------------------
__global__ __launch_bounds__(256) void k_sample(const ushort* __restrict__ vperm,
                                                const float* __restrict__ params,
                                                ushort* __restrict__ mid) {
    __shared__ float pm[8][264];   // per q: [h][33] padded
    const int b   = blockIdx.y;
    const int q0  = blockIdx.x * 8;
    const int t   = threadIdx.x;
    const int ql  = t >> 5;
    const int sub = t & 31;
    const int h   = sub >> 2;
    const int dh8 = sub & 3;

    for (int i = t; i < 8 * 256; i += 256) {
        const int q = i >> 8, c = i & 255;
        pm[q][(c >> 5) * 33 + (c & 31)] = params[((size_t)(b * NQ_ + q0 + q)) * 256 + c];
    }
    __syncthreads();

    const ushort* vb = vperm + ((size_t)(b * H_ + h)) * SLAB_ * 32 + dh8 * 8;
    const int po_[4] = {0, 4356, 5512, 5836};

    f32x8 acc = (f32x8)(0.f);
    #pragma unroll
    for (int l = 0; l < L_; ++l) {
        const int W2 = (64 >> l) + 2;
        const ushort* vl = vb + (size_t)po_[l] * 32;
        const float* p  = &pm[ql][h * 33 + l * 8];
        const float a0 = p[0], a1 = p[1], a2 = p[2], a3 = p[3];
        const float xA = p[4], xB = p[5], yA = p[6], yB = p[7];
        const float xa0 = floorf(xA), xb0 = floorf(xB);
        const float ya0 = floorf(yA), yb0 = floorf(yB);
        const float fxa = xA - xa0, fxb = xB - xb0;
        const float fya = yA - ya0, fyb = yB - yb0;
        const int pxa = (int)xa0 + 1, pxb = (int)xb0 + 1;
        const int pya = (int)ya0 + 1, pyb = (int)yb0 + 1;
        #pragma unroll
        for (int k = 0; k < 4; ++k) {
            const int   px = (k & 2) ? pxb : pxa;
            const int   py = (k & 1) ? pyb : pya;
            const float fx = (k & 2) ? fxb : fxa;
            const float fy = (k & 1) ? fyb : fya;
            const float ak = (k == 0) ? a0 : (k == 1) ? a1 : (k == 2) ? a2 : a3;
            const ushort* cp = vl + (size_t)(py * W2 + px) * 32;
            const u16x8 u00 = *(const u16x8*)cp;
            const u16x8 u10 = *(const u16x8*)(cp + 32);
            const u16x8 u01 = *(const u16x8*)(cp + W2 * 32);
            const u16x8 u11 = *(const u16x8*)(cp + (W2 + 1) * 32);
            const float gx = 1.f - fx, gy = 1.f - fy;
            const float w00 = ak * gx * gy, w10 = ak * fx * gy;
            const float w01 = ak * gx * fy, w11 = ak * fx * fy;
            #pragma unroll
            for (int e = 0; e < 8; ++e)
                acc[e] += bf2f(u00[e]) * w00 + bf2f(u10[e]) * w10
                        + bf2f(u01[e]) * w01 + bf2f(u11[e]) * w11;
        }
    }
    u16x8 o;
    #pragma unroll
    for (int e = 0; e < 8; ++e) o[e] = f2bf(acc[e]);
    *(u16x8*)&mid[((size_t)(b * NQ_ + q0 + ql)) * 256 + sub * 8] = o;
}

// ---------------------------------------------------------------------------
extern "C" void kernel_launch(void* const* d_in, const int* in_sizes, int n_in,
                              void* d_out, int out_size, void* d_ws, size_t ws_size,
                              hipStream_t stream) {
    const float* query = (const float*)d_in[0];
    const float* refp  = (const float*)d_in[1];
    const float* value = (const float*)d_in[2];
    const float* Wt = (const float*)d_in[5];
    const float* bt = (const float*)d_in[6];
    const float* Wf = (const float*)d_in[7];
    const float* bf = (const float*)d_in[8];
    const float* Wl = (const float*)d_in[9];
    const float* bl = (const float*)d_in[10];
    const float* Wp = (const float*)d_in[11];
    const float* bp = (const float*)d_in[12];
    const float* Wv = (const float*)d_in[13];
    const float* bv = (const float*)d_in[14];
    const float* Wo = (const float*)d_in[15];
    const float* bo = (const float*)d_in[16];

    // ws layout (16B-aligned offsets; qbf aliases params, midb aliases logits)
    char* wsb = (char*)d_ws;
    ushort* vperm  = (ushort*)wsb;                       // 12,156,928 B
    float*  params = (float*)(wsb + 12156928);           // 33,554,432 B
    ushort* qbf    = (ushort*)(wsb + 12156928);          // 16,777,216 B (alias)
    float*  logits = (float*)(wsb + 45711360);           // 37,748,736 B
    ushort* midb   = (ushort*)(wsb + 45711360);          // 16,777,216 B (alias)
    ushort* valbf  = (ushort*)(wsb + 83460096);          // 11,141,120 B
    ushort* Wvt    = (ushort*)(wsb + 94601216);          // 131,072 B
    ushort* Wot    = (ushort*)(wsb + 94732288);          // 131,072 B
    ushort* Wqt    = (ushort*)(wsb + 94863360);          // 147,456 B

    // all converts + slab zeroing in one launch
    k_prep<<<10584, 256, 0, stream>>>(query, value, Wv, Wo, Wt, Wf, Wl, Wp,
                                      qbf, valbf, (uint4*)vperm, Wvt, Wot, Wqt);
    // value projection -> padded bf16 slabs
    k_gemm<128, 1><<<dim3(170, 2), 256, 0, stream>>>(valbf, Wvt, bv, vperm);
    // query projections -> raw logits
    k_gemm<96, 2><<<dim3(256, 3), 256, 0, stream>>>(qbf, Wqt, nullptr, logits);
    // epilogue -> params (overwrites qbf; dead)
    k_epi<<<4096, 256, 0, stream>>>(logits, refp, bt, bf, bl, bp, params);
    // bilinear sampling + attention -> bf16 mid (overwrites logits; dead)
    k_sample<<<dim3(NQ_ / 8, B_), 256, 0, stream>>>(vperm, params, midb);
    // output projection
    k_gemm<128, 0><<<dim3(256, 2), 256, 0, stream>>>(midb, Wot, bo, (float*)d_out);
}